// Round 6
// baseline (237.162 us; speedup 1.0000x reference)
//
#include <hip/hip_runtime.h>
#include <hip/hip_bf16.h>

// DilatedMSA round 11: persistent 256-block pipeline, dbuf K/V LDS.
//  - 1 block/CU (grid 256), 8 waves x 32 tokens; each block owns 4 items
//    (bl,h): {2b,0},{2b,1},{2b+1,0},{2b+1,1}. No dispatch rounds, no tail.
//  - Double-buffered K/V (141 KB LDS): attn(item i) reads buf[i&1] while the
//    same waves run GEMM(item i+1) into buf[i+1&1] -> ONE barrier per item,
//    cross-phase overlap on every pipe (r9/r10 were lockstep GEMM|barrier|attn).
//  - x loaded once per bl (shared by both heads); x for items 2-3 prefetched
//    (issue-early/write-late) during item 1's attention.
//  - All GEMMs on 32x32x16 MFMA (half the MFMA instructions of r9, same FLOPs),
//    attn identical math to r10 (in-register P via cvt_pk + permlane32_swap).

typedef __bf16 bf16x8 __attribute__((ext_vector_type(8)));
typedef float  f32x16 __attribute__((ext_vector_type(16)));

#define MFMA32(a, b, c) __builtin_amdgcn_mfma_f32_32x32x16_bf16((a), (b), (c), 0, 0, 0)

namespace dmsa {

constexpr int G  = 256;    // tokens per (b,l)
constexpr int C  = 128;    // channels
constexpr int HD = 64;     // head dim
// fold log2(e)/sqrt(128) into Q -> attn does exp2(s) directly
constexpr float QSCALE = 1.4426950408889634f * 0.08838834764831845f;

__device__ __forceinline__ unsigned pack2(float a, float b) {
    union { __hip_bfloat162 h; unsigned u; } c;
    c.h = __float22bfloat162_rn(make_float2(a, b));   // v_cvt_pk_bf16_f32
    return c.u;
}
__device__ __forceinline__ uint2 pack4(float a, float b, float c, float d) {
    uint2 r; r.x = pack2(a, b); r.y = pack2(c, d); return r;
}
__device__ __forceinline__ uint4 pack8(const float* p) {
    uint4 r;
    r.x = pack2(p[0], p[1]); r.y = pack2(p[2], p[3]);
    r.z = pack2(p[4], p[5]); r.w = pack2(p[6], p[7]);
    return r;
}
__device__ __forceinline__ bf16x8 lds8(const ushort* p) { return *(const bf16x8*)p; }
__device__ __forceinline__ bf16x8 ldg8(const ushort* p) { return *(const bf16x8*)p; }

// ---------------------------------------------------------------------------
// K0: W [384][128] fp32 -> bf16.
// ---------------------------------------------------------------------------
__global__ void convw(const float* __restrict__ W, ushort* __restrict__ wbf) {
    int t = blockIdx.x * 256 + threadIdx.x;
    float tmp[8];
    const float* p = W + (size_t)t * 8;
    *(float4*)tmp       = *(const float4*)p;
    *(float4*)(tmp + 4) = *(const float4*)(p + 4);
    *(uint4*)(wbf + (size_t)t * 8) = pack8(tmp);
}

// ---------------------------------------------------------------------------
// K1: grid 256, block 512 (8 waves x 32 tokens). LDS 141312 B -> 1 block/CU.
// ---------------------------------------------------------------------------
__global__ __launch_bounds__(512, 2)
void fused(const float* __restrict__ x, const ushort* __restrict__ wb,
           const float* __restrict__ bias, float* __restrict__ out)
{
    __shared__ ushort kcs[2][G * 72];    // K [256 g][64 c' +pad8]; Q-stage first
    __shared__ ushort vcs[2][HD * 264];  // V^T [64 c'][256 g +pad8]

    const int tid = threadIdx.x, wv = tid >> 6, lane = tid & 63;
    const int l32 = lane & 31, hl = lane >> 5;
    const int r0 = wv * 32;              // wave's tokens AND queries
    const int b = blockIdx.x;            // 256 blocks x 4 items

    // ---- x prefetch (fp32 raw) + one-time bf16 conversion per bl
    float4 xraw[16];
    auto issue_x = [&](int nbl) {
        const float* px = x + ((size_t)nbl * G + r0 + l32) * C + hl * 8;
        #pragma unroll
        for (int kk = 0; kk < 8; ++kk) {
            xraw[2 * kk]     = *(const float4*)(px + kk * 16);
            xraw[2 * kk + 1] = *(const float4*)(px + kk * 16 + 4);
        }
    };
    bf16x8 xf[8];                        // B/A-frag [row=l32][k=kk*16+hl*8+j]
    auto cvt_x = [&]() {
        #pragma unroll
        for (int kk = 0; kk < 8; ++kk) {
            union { uint4 u; bf16x8 v; } c;
            c.u = pack8((const float*)&xraw[2 * kk]);
            xf[kk] = c.v;
        }
    };

    bf16x8 qf[4];                        // Q B-frag [n=q=l32][k=c']
    // ---- qkv GEMM for one (item) head into (kcb, vcb); 48 MFMA32 per wave.
    auto do_gemm = [&](int h_, ushort* kcb, ushort* vcb) {
        const ushort* Wq = wb + (size_t)(h_ * HD) * C;
        const ushort* Wk = wb + (size_t)(C + h_ * HD) * C;
        const ushort* Wv = wb + (size_t)(2 * C + h_ * HD) * C;

        // Q^T [c' 64 (2 mt)][q 32]: A=Wq (m=c'), B=xf (n=tok)
        f32x16 qa[2];
        #pragma unroll
        for (int mt = 0; mt < 2; ++mt)
            #pragma unroll
            for (int r = 0; r < 16; ++r) qa[mt][r] = 0.f;
        #pragma unroll
        for (int kk = 0; kk < 8; ++kk)
            #pragma unroll
            for (int mt = 0; mt < 2; ++mt) {
                bf16x8 a = ldg8(Wq + (size_t)(mt * 32 + l32) * C + kk * 16 + hl * 8);
                qa[mt] = MFMA32(a, xf[kk], qa[mt]);
            }
        // Q epi -> qs[q][c'] (wave-private rows r0..+32 of kcb), +bias *QSCALE
        // C/D: col=q=l32, row=c' = (e&3)+8*(e>>2)+4*hl+32*mt
        ushort* qs = kcb + r0 * 72;
        #pragma unroll
        for (int mt = 0; mt < 2; ++mt)
            #pragma unroll
            for (int j = 0; j < 4; ++j) {
                int c0 = mt * 32 + j * 8 + hl * 4;
                float4 bs = *(const float4*)(bias + h_ * HD + c0);
                *(uint2*)(qs + l32 * 72 + c0) =
                    pack4((qa[mt][4 * j + 0] + bs.x) * QSCALE,
                          (qa[mt][4 * j + 1] + bs.y) * QSCALE,
                          (qa[mt][4 * j + 2] + bs.z) * QSCALE,
                          (qa[mt][4 * j + 3] + bs.w) * QSCALE);
            }
        #pragma unroll
        for (int kk = 0; kk < 4; ++kk)       // readback BEFORE K-epi overwrites
            qf[kk] = lds8(qs + l32 * 72 + kk * 16 + hl * 8);

        // K^T: identical orientation; epi -> kcb[tok][c'] (col=tok=l32)
        f32x16 ka[2];
        #pragma unroll
        for (int mt = 0; mt < 2; ++mt)
            #pragma unroll
            for (int r = 0; r < 16; ++r) ka[mt][r] = 0.f;
        #pragma unroll
        for (int kk = 0; kk < 8; ++kk)
            #pragma unroll
            for (int mt = 0; mt < 2; ++mt) {
                bf16x8 a = ldg8(Wk + (size_t)(mt * 32 + l32) * C + kk * 16 + hl * 8);
                ka[mt] = MFMA32(a, xf[kk], ka[mt]);
            }
        #pragma unroll
        for (int mt = 0; mt < 2; ++mt)
            #pragma unroll
            for (int j = 0; j < 4; ++j) {
                int c0 = mt * 32 + j * 8 + hl * 4;
                float4 bs = *(const float4*)(bias + C + h_ * HD + c0);
                *(uint2*)(kcb + (r0 + l32) * 72 + c0) =
                    pack4(ka[mt][4 * j + 0] + bs.x, ka[mt][4 * j + 1] + bs.y,
                          ka[mt][4 * j + 2] + bs.z, ka[mt][4 * j + 3] + bs.w);
            }

        // V: A=xf (m=tok), B=Wv (n=c'); epi -> vcb[c'][tok] (col=c'=l32)
        f32x16 va[2];
        #pragma unroll
        for (int nt = 0; nt < 2; ++nt)
            #pragma unroll
            for (int r = 0; r < 16; ++r) va[nt][r] = 0.f;
        #pragma unroll
        for (int kk = 0; kk < 8; ++kk)
            #pragma unroll
            for (int nt = 0; nt < 2; ++nt) {
                bf16x8 bw = ldg8(Wv + (size_t)(nt * 32 + l32) * C + kk * 16 + hl * 8);
                va[nt] = MFMA32(xf[kk], bw, va[nt]);
            }
        #pragma unroll
        for (int nt = 0; nt < 2; ++nt) {
            float bv = bias[2 * C + h_ * HD + nt * 32 + l32];
            #pragma unroll
            for (int j = 0; j < 4; ++j) {
                int t0 = j * 8 + hl * 4;   // tok rows r+8j+4hl
                *(uint2*)(vcb + (nt * 32 + l32) * 264 + r0 + t0) =
                    pack4(va[nt][4 * j + 0] + bv, va[nt][4 * j + 1] + bv,
                          va[nt][4 * j + 2] + bv, va[nt][4 * j + 3] + bv);
            }
        }
    };

    // ---- prologue: item 0 (bl=2b, h=0)
    issue_x(2 * b);
    cvt_x();
    do_gemm(0, kcs[0], vcs[0]);
    __syncthreads();

    // ---- 4-item pipeline: attn(it) on buf[it&1]  ||  gemm(it+1) -> buf[it+1&1]
    #pragma unroll 1
    for (int it = 0; it < 4; ++it) {
        const int L = 4 * b + it, bl = L >> 1, h = L & 1, cur = it & 1;
        ushort* kcb = kcs[cur];
        ushort* vcb = vcs[cur];

        f32x16 oacc[2];
        #pragma unroll
        for (int mt = 0; mt < 2; ++mt)
            #pragma unroll
            for (int r = 0; r < 16; ++r) oacc[mt][r] = 0.f;
        float lacc = 0.f;

        // 4 strips x 64 keys; two independent S-chains (mi) per strip.
        #pragma unroll
        for (int sp = 0; sp < 4; ++sp) {
            if (it == 1 && sp == 3) issue_x(2 * b + 1);   // prefetch next bl's x

            bf16x8 kf[2][4];       // A[m=gk=mi*32+l32][k=c' kk*16+hl*8]
            #pragma unroll
            for (int mi = 0; mi < 2; ++mi)
                #pragma unroll
                for (int kk = 0; kk < 4; ++kk)
                    kf[mi][kk] = lds8(kcb + (sp * 64 + mi * 32 + l32) * 72
                                      + kk * 16 + hl * 8);

            f32x16 s[2];           // S^T col=q=l32, row=gk
            #pragma unroll
            for (int mi = 0; mi < 2; ++mi)
                #pragma unroll
                for (int r = 0; r < 16; ++r) s[mi][r] = 0.f;
            #pragma unroll
            for (int kk = 0; kk < 4; ++kk)
                #pragma unroll
                for (int mi = 0; mi < 2; ++mi)
                    s[mi] = MFMA32(kf[mi][kk], qf[kk], s[mi]);

            // single-pass softmax: p = exp2(s) (scale folded into Q)
            float part = 0.f;
            #pragma unroll
            for (int mi = 0; mi < 2; ++mi)
                #pragma unroll
                for (int r = 0; r < 16; ++r) {
                    float p = exp2f(s[mi][r]);
                    s[mi][r] = p;
                    part += p;
                }
            lacc += part;

            // P -> PV B-frag in registers (cvt_pk + permlane32_swap), then PV
            #pragma unroll
            for (int mi = 0; mi < 2; ++mi)
                #pragma unroll
                for (int ch = 0; ch < 2; ++ch) {
                    unsigned p0a = pack2(s[mi][8 * ch + 0], s[mi][8 * ch + 1]);
                    unsigned p0b = pack2(s[mi][8 * ch + 2], s[mi][8 * ch + 3]);
                    unsigned p1a = pack2(s[mi][8 * ch + 4], s[mi][8 * ch + 5]);
                    unsigned p1b = pack2(s[mi][8 * ch + 6], s[mi][8 * ch + 7]);
                    auto w02 = __builtin_amdgcn_permlane32_swap((int)p0a, (int)p1a, false, false);
                    auto w13 = __builtin_amdgcn_permlane32_swap((int)p0b, (int)p1b, false, false);
                    union { uint4 u; bf16x8 v; } pf;
                    pf.u.x = (unsigned)w02[0]; pf.u.y = (unsigned)w13[0];
                    pf.u.z = (unsigned)w02[1]; pf.u.w = (unsigned)w13[1];
                    const int cc = 2 * mi + ch;   // 16-key chunk within strip
                    #pragma unroll
                    for (int mt = 0; mt < 2; ++mt) {
                        bf16x8 vf = lds8(vcb + (mt * 32 + l32) * 264
                                         + sp * 64 + cc * 16 + hl * 8);
                        oacc[mt] = MFMA32(vf, pf.v, oacc[mt]);
                    }
                }
        }

        // ---- store item's output: O^T col=q=l32, row=c'
        float l = lacc + __shfl_xor(lacc, 32);
        float inv = 1.0f / l;
        float* og = out + (size_t)bl * G * C + h * HD + (size_t)(r0 + l32) * C;
        #pragma unroll
        for (int mt = 0; mt < 2; ++mt)
            #pragma unroll
            for (int rr = 0; rr < 4; ++rr) {
                float4 st;
                st.x = oacc[mt][4 * rr + 0] * inv;
                st.y = oacc[mt][4 * rr + 1] * inv;
                st.z = oacc[mt][4 * rr + 2] * inv;
                st.w = oacc[mt][4 * rr + 3] * inv;
                *(float4*)(og + mt * 32 + rr * 8 + hl * 4) = st;
            }

        // ---- next item's GEMM into the other buffer (overlaps other waves' attn)
        if (it < 3) {
            if (it == 1) cvt_x();            // new bl's x (prefetched at sp==3)
            do_gemm((it + 1) & 1, kcs[cur ^ 1], vcs[cur ^ 1]);
        }
        __syncthreads();                     // buf[cur^1] ready; attn(it) reads done
    }
}

} // namespace dmsa

extern "C" void kernel_launch(void* const* d_in, const int* in_sizes, int n_in,
                              void* d_out, int out_size, void* d_ws, size_t ws_size,
                              hipStream_t stream) {
    (void)in_sizes; (void)n_in; (void)out_size;

    if (ws_size < (size_t)384 * 128 * 2) return;   // 96 KB W-bf16 scratch

    const float* x    = (const float*)d_in[0];
    const float* W    = (const float*)d_in[1];
    const float* bias = (const float*)d_in[2];
    float* out = (float*)d_out;

    ushort* wbf = (ushort*)d_ws;

    dmsa::convw<<<dim3(24),  dim3(256), 0, stream>>>(W, wbf);
    dmsa::fused<<<dim3(256), dim3(512), 0, stream>>>(x, wbf, bias, out);
}

// Round 7
// 183.128 us; speedup vs baseline: 1.2951x; 1.2951x over previous
//
#include <hip/hip_runtime.h>
#include <hip/hip_bf16.h>

// DilatedMSA round 12: r11 persistent pipeline, SPILL-FIXED.
//  r11's __launch_bounds__(512,2) capped VGPR at 128 -> ~100 regs spilled ->
//  380 MB scratch traffic (WRITE_SIZE 221 MB) -> 165us. This round:
//   - no VGPR cap (launch_bounds(512) only; ~220 regs fits 8 waves/CU budget)
//   - xraw[16] prefetch file deleted: x is loaded+converted into xf directly
//     at the start of the item that precedes its first use (xf is dead during
//     item-1 attn, so the new bl's HBM latency still hides under attention).
//  Structure unchanged from r11: grid 256 (1 block/CU), 8 waves x 32 tokens,
//  4 items (bl,h) per block, dbuf K/V LDS (141 KB), one barrier per item,
//  32x32x16 GEMMs, in-register P via cvt_pk + permlane32_swap.

typedef __bf16 bf16x8 __attribute__((ext_vector_type(8)));
typedef float  f32x16 __attribute__((ext_vector_type(16)));

#define MFMA32(a, b, c) __builtin_amdgcn_mfma_f32_32x32x16_bf16((a), (b), (c), 0, 0, 0)

namespace dmsa {

constexpr int G  = 256;    // tokens per (b,l)
constexpr int C  = 128;    // channels
constexpr int HD = 64;     // head dim
// fold log2(e)/sqrt(128) into Q -> attn does exp2(s) directly
constexpr float QSCALE = 1.4426950408889634f * 0.08838834764831845f;

__device__ __forceinline__ unsigned pack2(float a, float b) {
    union { __hip_bfloat162 h; unsigned u; } c;
    c.h = __float22bfloat162_rn(make_float2(a, b));   // v_cvt_pk_bf16_f32
    return c.u;
}
__device__ __forceinline__ uint2 pack4(float a, float b, float c, float d) {
    uint2 r; r.x = pack2(a, b); r.y = pack2(c, d); return r;
}
__device__ __forceinline__ uint4 pack8(const float* p) {
    uint4 r;
    r.x = pack2(p[0], p[1]); r.y = pack2(p[2], p[3]);
    r.z = pack2(p[4], p[5]); r.w = pack2(p[6], p[7]);
    return r;
}
__device__ __forceinline__ bf16x8 lds8(const ushort* p) { return *(const bf16x8*)p; }
__device__ __forceinline__ bf16x8 ldg8(const ushort* p) { return *(const bf16x8*)p; }
// 8 consecutive fp32 -> bf16x8 fragment
__device__ __forceinline__ bf16x8 ld8f(const float* __restrict__ p) {
    float t[8];
    *(float4*)t       = *(const float4*)p;
    *(float4*)(t + 4) = *(const float4*)(p + 4);
    union { uint4 u; bf16x8 v; } c;
    c.u = pack8(t);
    return c.v;
}

// ---------------------------------------------------------------------------
// K0: W [384][128] fp32 -> bf16.
// ---------------------------------------------------------------------------
__global__ void convw(const float* __restrict__ W, ushort* __restrict__ wbf) {
    int t = blockIdx.x * 256 + threadIdx.x;
    float tmp[8];
    const float* p = W + (size_t)t * 8;
    *(float4*)tmp       = *(const float4*)p;
    *(float4*)(tmp + 4) = *(const float4*)(p + 4);
    *(uint4*)(wbf + (size_t)t * 8) = pack8(tmp);
}

// ---------------------------------------------------------------------------
// K1: grid 256, block 512 (8 waves x 32 tokens). LDS 141312 B -> 1 block/CU.
// ---------------------------------------------------------------------------
__global__ __launch_bounds__(512)
void fused(const float* __restrict__ x, const ushort* __restrict__ wb,
           const float* __restrict__ bias, float* __restrict__ out)
{
    __shared__ ushort kcs[2][G * 72];    // K [256 g][64 c' +pad8]; Q-stage first
    __shared__ ushort vcs[2][HD * 264];  // V^T [64 c'][256 g +pad8]

    const int tid = threadIdx.x, wv = tid >> 6, lane = tid & 63;
    const int l32 = lane & 31, hl = lane >> 5;
    const int r0 = wv * 32;              // wave's tokens AND queries
    const int b = blockIdx.x;            // 256 blocks x 4 items

    // ---- x fragments (bf16, converted once per bl, reused by Q/K/V GEMMs)
    bf16x8 xf[8];                        // B/A-frag [row=l32][k=kk*16+hl*8+j]
    auto load_x = [&](int nbl) {
        const float* px = x + ((size_t)nbl * G + r0 + l32) * C + hl * 8;
        #pragma unroll
        for (int kk = 0; kk < 8; ++kk)
            xf[kk] = ld8f(px + kk * 16);
    };

    bf16x8 qf[4];                        // Q B-frag [n=q=l32][k=c']
    // ---- qkv GEMM for one (item) head into (kcb, vcb); 48 MFMA32 per wave.
    auto do_gemm = [&](int h_, ushort* kcb, ushort* vcb) {
        const ushort* Wq = wb + (size_t)(h_ * HD) * C;
        const ushort* Wk = wb + (size_t)(C + h_ * HD) * C;
        const ushort* Wv = wb + (size_t)(2 * C + h_ * HD) * C;

        // Q^T [c' 64 (2 mt)][q 32]: A=Wq (m=c'), B=xf (n=tok)
        f32x16 qa[2];
        #pragma unroll
        for (int mt = 0; mt < 2; ++mt)
            #pragma unroll
            for (int r = 0; r < 16; ++r) qa[mt][r] = 0.f;
        #pragma unroll
        for (int kk = 0; kk < 8; ++kk)
            #pragma unroll
            for (int mt = 0; mt < 2; ++mt) {
                bf16x8 a = ldg8(Wq + (size_t)(mt * 32 + l32) * C + kk * 16 + hl * 8);
                qa[mt] = MFMA32(a, xf[kk], qa[mt]);
            }
        // Q epi -> qs[q][c'] (wave-private rows r0..+32 of kcb), +bias *QSCALE
        // C/D: col=q=l32, row=c' = (e&3)+8*(e>>2)+4*hl+32*mt
        ushort* qs = kcb + r0 * 72;
        #pragma unroll
        for (int mt = 0; mt < 2; ++mt)
            #pragma unroll
            for (int j = 0; j < 4; ++j) {
                int c0 = mt * 32 + j * 8 + hl * 4;
                float4 bs = *(const float4*)(bias + h_ * HD + c0);
                *(uint2*)(qs + l32 * 72 + c0) =
                    pack4((qa[mt][4 * j + 0] + bs.x) * QSCALE,
                          (qa[mt][4 * j + 1] + bs.y) * QSCALE,
                          (qa[mt][4 * j + 2] + bs.z) * QSCALE,
                          (qa[mt][4 * j + 3] + bs.w) * QSCALE);
            }
        #pragma unroll
        for (int kk = 0; kk < 4; ++kk)       // readback BEFORE K-epi overwrites
            qf[kk] = lds8(qs + l32 * 72 + kk * 16 + hl * 8);

        // K^T: identical orientation; epi -> kcb[tok][c'] (col=tok=l32)
        f32x16 ka[2];
        #pragma unroll
        for (int mt = 0; mt < 2; ++mt)
            #pragma unroll
            for (int r = 0; r < 16; ++r) ka[mt][r] = 0.f;
        #pragma unroll
        for (int kk = 0; kk < 8; ++kk)
            #pragma unroll
            for (int mt = 0; mt < 2; ++mt) {
                bf16x8 a = ldg8(Wk + (size_t)(mt * 32 + l32) * C + kk * 16 + hl * 8);
                ka[mt] = MFMA32(a, xf[kk], ka[mt]);
            }
        #pragma unroll
        for (int mt = 0; mt < 2; ++mt)
            #pragma unroll
            for (int j = 0; j < 4; ++j) {
                int c0 = mt * 32 + j * 8 + hl * 4;
                float4 bs = *(const float4*)(bias + C + h_ * HD + c0);
                *(uint2*)(kcb + (r0 + l32) * 72 + c0) =
                    pack4(ka[mt][4 * j + 0] + bs.x, ka[mt][4 * j + 1] + bs.y,
                          ka[mt][4 * j + 2] + bs.z, ka[mt][4 * j + 3] + bs.w);
            }

        // V: A=xf (m=tok), B=Wv (n=c'); epi -> vcb[c'][tok] (col=c'=l32)
        f32x16 va[2];
        #pragma unroll
        for (int nt = 0; nt < 2; ++nt)
            #pragma unroll
            for (int r = 0; r < 16; ++r) va[nt][r] = 0.f;
        #pragma unroll
        for (int kk = 0; kk < 8; ++kk)
            #pragma unroll
            for (int nt = 0; nt < 2; ++nt) {
                bf16x8 bw = ldg8(Wv + (size_t)(nt * 32 + l32) * C + kk * 16 + hl * 8);
                va[nt] = MFMA32(xf[kk], bw, va[nt]);
            }
        #pragma unroll
        for (int nt = 0; nt < 2; ++nt) {
            float bv = bias[2 * C + h_ * HD + nt * 32 + l32];
            #pragma unroll
            for (int j = 0; j < 4; ++j) {
                int t0 = j * 8 + hl * 4;   // tok rows r+8j+4hl
                *(uint2*)(vcb + (nt * 32 + l32) * 264 + r0 + t0) =
                    pack4(va[nt][4 * j + 0] + bv, va[nt][4 * j + 1] + bv,
                          va[nt][4 * j + 2] + bv, va[nt][4 * j + 3] + bv);
            }
        }
    };

    // ---- prologue: item 0 (bl=2b, h=0)
    load_x(2 * b);
    do_gemm(0, kcs[0], vcs[0]);
    __syncthreads();

    // ---- 4-item pipeline: attn(it) on buf[it&1]  ||  gemm(it+1) -> buf[it+1&1]
    #pragma unroll 1
    for (int it = 0; it < 4; ++it) {
        const int L = 4 * b + it, bl = L >> 1, h = L & 1, cur = it & 1;
        ushort* kcb = kcs[cur];
        ushort* vcb = vcs[cur];

        // xf is dead during item-1 attn (item-1's gemm already consumed it);
        // load the next bl's x here so HBM latency hides under this attention.
        if (it == 1) load_x(2 * b + 1);

        f32x16 oacc[2];
        #pragma unroll
        for (int mt = 0; mt < 2; ++mt)
            #pragma unroll
            for (int r = 0; r < 16; ++r) oacc[mt][r] = 0.f;
        float lacc = 0.f;

        // 4 strips x 64 keys; two independent S-chains (mi) per strip.
        #pragma unroll
        for (int sp = 0; sp < 4; ++sp) {
            bf16x8 kf[2][4];       // A[m=gk=mi*32+l32][k=c' kk*16+hl*8]
            #pragma unroll
            for (int mi = 0; mi < 2; ++mi)
                #pragma unroll
                for (int kk = 0; kk < 4; ++kk)
                    kf[mi][kk] = lds8(kcb + (sp * 64 + mi * 32 + l32) * 72
                                      + kk * 16 + hl * 8);

            f32x16 s[2];           // S^T col=q=l32, row=gk
            #pragma unroll
            for (int mi = 0; mi < 2; ++mi)
                #pragma unroll
                for (int r = 0; r < 16; ++r) s[mi][r] = 0.f;
            #pragma unroll
            for (int kk = 0; kk < 4; ++kk)
                #pragma unroll
                for (int mi = 0; mi < 2; ++mi)
                    s[mi] = MFMA32(kf[mi][kk], qf[kk], s[mi]);

            // single-pass softmax: p = exp2(s) (scale folded into Q)
            float part = 0.f;
            #pragma unroll
            for (int mi = 0; mi < 2; ++mi)
                #pragma unroll
                for (int r = 0; r < 16; ++r) {
                    float p = exp2f(s[mi][r]);
                    s[mi][r] = p;
                    part += p;
                }
            lacc += part;

            // P -> PV B-frag in registers (cvt_pk + permlane32_swap), then PV
            #pragma unroll
            for (int mi = 0; mi < 2; ++mi)
                #pragma unroll
                for (int ch = 0; ch < 2; ++ch) {
                    unsigned p0a = pack2(s[mi][8 * ch + 0], s[mi][8 * ch + 1]);
                    unsigned p0b = pack2(s[mi][8 * ch + 2], s[mi][8 * ch + 3]);
                    unsigned p1a = pack2(s[mi][8 * ch + 4], s[mi][8 * ch + 5]);
                    unsigned p1b = pack2(s[mi][8 * ch + 6], s[mi][8 * ch + 7]);
                    auto w02 = __builtin_amdgcn_permlane32_swap((int)p0a, (int)p1a, false, false);
                    auto w13 = __builtin_amdgcn_permlane32_swap((int)p0b, (int)p1b, false, false);
                    union { uint4 u; bf16x8 v; } pf;
                    pf.u.x = (unsigned)w02[0]; pf.u.y = (unsigned)w13[0];
                    pf.u.z = (unsigned)w02[1]; pf.u.w = (unsigned)w13[1];
                    const int cc = 2 * mi + ch;   // 16-key chunk within strip
                    #pragma unroll
                    for (int mt = 0; mt < 2; ++mt) {
                        bf16x8 vf = lds8(vcb + (mt * 32 + l32) * 264
                                         + sp * 64 + cc * 16 + hl * 8);
                        oacc[mt] = MFMA32(vf, pf.v, oacc[mt]);
                    }
                }
        }

        // ---- store item's output: O^T col=q=l32, row=c'
        float l = lacc + __shfl_xor(lacc, 32);
        float inv = 1.0f / l;
        float* og = out + (size_t)bl * G * C + h * HD + (size_t)(r0 + l32) * C;
        #pragma unroll
        for (int mt = 0; mt < 2; ++mt)
            #pragma unroll
            for (int rr = 0; rr < 4; ++rr) {
                float4 st;
                st.x = oacc[mt][4 * rr + 0] * inv;
                st.y = oacc[mt][4 * rr + 1] * inv;
                st.z = oacc[mt][4 * rr + 2] * inv;
                st.w = oacc[mt][4 * rr + 3] * inv;
                *(float4*)(og + mt * 32 + rr * 8 + hl * 4) = st;
            }

        // ---- next item's GEMM into the other buffer (same scheduling region
        //      as this item's attn tail: compiler interleaves loads/MFMA)
        if (it < 3)
            do_gemm((it + 1) & 1, kcs[cur ^ 1], vcs[cur ^ 1]);
        __syncthreads();                     // buf[cur^1] ready; attn(it) reads done
    }
}

} // namespace dmsa

extern "C" void kernel_launch(void* const* d_in, const int* in_sizes, int n_in,
                              void* d_out, int out_size, void* d_ws, size_t ws_size,
                              hipStream_t stream) {
    (void)in_sizes; (void)n_in; (void)out_size;

    if (ws_size < (size_t)384 * 128 * 2) return;   // 96 KB W-bf16 scratch

    const float* x    = (const float*)d_in[0];
    const float* W    = (const float*)d_in[1];
    const float* bias = (const float*)d_in[2];
    float* out = (float*)d_out;

    ushort* wbf = (ushort*)d_ws;

    dmsa::convw<<<dim3(24),  dim3(256), 0, stream>>>(W, wbf);
    dmsa::fused<<<dim3(256), dim3(512), 0, stream>>>(x, wbf, bias, out);
}

// Round 8
// 158.260 us; speedup vs baseline: 1.4986x; 1.1571x over previous
//
#include <hip/hip_runtime.h>
#include <hip/hip_bf16.h>

// DilatedMSA round 13: r9 (best measured: fused 81us) + phase de-correlation.
//  - Base structure identical to r9: grid 1024=(bl,h), block 256 (4 waves x
//    64 tokens), LDS 70.7KB (2 blocks/CU), one barrier, 16x16 GEMMs,
//    32x32 attn with in-register P (cvt_pk + permlane32_swap).
//  - NEW: wave- and block-staggered strip order in attention
//    (sp_eff = (sp + 2*wv + 4*(b&1)) & 7). All waves leave the barrier into
//    the same code, but now co-resident waves sit in DIFFERENT micro-phases
//    (LDS-read vs MFMA vs softmax) -> stalls de-correlate, TLP actually bites.
//  - NEW: __builtin_amdgcn_exp2f (single v_exp_f32; drops ocml fixup from the
//    256-op trans chain; |s| small so approx is safe).

typedef __bf16 bf16x8 __attribute__((ext_vector_type(8)));
typedef float  f32x4  __attribute__((ext_vector_type(4)));
typedef float  f32x16 __attribute__((ext_vector_type(16)));

#define MFMA16(a, b, c) __builtin_amdgcn_mfma_f32_16x16x32_bf16((a), (b), (c), 0, 0, 0)
#define MFMA32(a, b, c) __builtin_amdgcn_mfma_f32_32x32x16_bf16((a), (b), (c), 0, 0, 0)

namespace dmsa {

constexpr int G  = 256;    // tokens per (b,l)
constexpr int C  = 128;    // channels
constexpr int HD = 64;     // head dim
// fold log2(e)/sqrt(128) into Q -> attn does exp2(s) directly
constexpr float QSCALE = 1.4426950408889634f * 0.08838834764831845f;

__device__ __forceinline__ unsigned pack2(float a, float b) {
    union { __hip_bfloat162 h; unsigned u; } c;
    c.h = __float22bfloat162_rn(make_float2(a, b));   // v_cvt_pk_bf16_f32
    return c.u;
}
__device__ __forceinline__ uint2 pack4(float a, float b, float c, float d) {
    uint2 r; r.x = pack2(a, b); r.y = pack2(c, d); return r;
}
__device__ __forceinline__ uint4 pack8(const float* p) {
    uint4 r;
    r.x = pack2(p[0], p[1]); r.y = pack2(p[2], p[3]);
    r.z = pack2(p[4], p[5]); r.w = pack2(p[6], p[7]);
    return r;
}
__device__ __forceinline__ bf16x8 lds8(const ushort* p) { return *(const bf16x8*)p; }
__device__ __forceinline__ bf16x8 ldg8(const ushort* p) { return *(const bf16x8*)p; }
// 8 consecutive fp32 -> bf16x8 fragment
__device__ __forceinline__ bf16x8 ld8f(const float* __restrict__ p) {
    float t[8];
    *(float4*)t       = *(const float4*)p;
    *(float4*)(t + 4) = *(const float4*)(p + 4);
    union { uint4 u; bf16x8 v; } c;
    c.u = pack8(t);
    return c.v;
}

// ---------------------------------------------------------------------------
// K0: W [384][128] fp32 -> bf16.
// ---------------------------------------------------------------------------
__global__ void convw(const float* __restrict__ W, ushort* __restrict__ wbf) {
    int t = blockIdx.x * 256 + threadIdx.x;
    float tmp[8];
    const float* p = W + (size_t)t * 8;
    *(float4*)tmp       = *(const float4*)p;
    *(float4*)(tmp + 4) = *(const float4*)(p + 4);
    *(uint4*)(wbf + (size_t)t * 8) = pack8(tmp);
}

// ---------------------------------------------------------------------------
// K1: grid 1024 = (bl 512) x (h 2), block 256 (4 waves).
// Wave wv owns tokens/queries wv*64..+64 for the GEMMs and attention.
// ---------------------------------------------------------------------------
__global__ __launch_bounds__(256, 2)
void fused(const float* __restrict__ x, const ushort* __restrict__ wb,
           const float* __restrict__ bias, float* __restrict__ out)
{
    __shared__ ushort kc[G * 72];        // K [256 g][64 c' +pad8]; Q-stage first
    __shared__ ushort vc[HD * 264];      // V^T [64 c'][256 g +pad8]

    const int tid = threadIdx.x, wv = tid >> 6, lane = tid & 63;
    const int l16 = lane & 15, quad = lane >> 4;
    const int l32 = lane & 31, hl = lane >> 5;

    // XCD-chunked bijective swizzle (1024 % 8 == 0): h=0/1 of one bl colocate.
    const int b  = blockIdx.x;
    const int L  = ((b & 7) << 7) | (b >> 3);
    const int bl = L >> 1, h = L & 1;

    const float*  xr = x  + (size_t)bl * G * C;
    const ushort* Wq = wb + (size_t)(h * HD) * C;
    const ushort* Wk = wb + (size_t)(C + h * HD) * C;
    const ushort* Wv = wb + (size_t)(2 * C + h * HD) * C;

    const int r0 = wv * 64;
    const f32x4 z4 = {0.f, 0.f, 0.f, 0.f};

    // ---- x fragments: fp32 -> bf16 ONCE, reused by Q(B), K(B), V(A) GEMMs.
    bf16x8 xf[4][4];   // [16-row tile][32-ch chunk]
    #pragma unroll
    for (int i = 0; i < 4; ++i)
        #pragma unroll
        for (int kk = 0; kk < 4; ++kk)
            xf[i][kk] = ld8f(xr + (size_t)(r0 + i * 16 + l16) * C + kk * 32 + quad * 8);

    // ---- Q-GEMM: Q^T [c'][q]. A=Wq (m=c', 4 tiles), B=xf.
    f32x4 qacc[4][4];
    #pragma unroll
    for (int mi = 0; mi < 4; ++mi)
        #pragma unroll
        for (int ni = 0; ni < 4; ++ni) qacc[mi][ni] = z4;
    #pragma unroll
    for (int kk = 0; kk < 4; ++kk)
        #pragma unroll
        for (int mi = 0; mi < 4; ++mi) {
            bf16x8 a = ldg8(Wq + (size_t)(mi * 16 + l16) * C + kk * 32 + quad * 8);
            #pragma unroll
            for (int ni = 0; ni < 4; ++ni)
                qacc[mi][ni] = MFMA16(a, xf[ni][kk], qacc[mi][ni]);
        }
    // stage to wave-private kc slice (+bias, *QSCALE): qs[q][c']
    ushort* qs = kc + r0 * 72;
    #pragma unroll
    for (int mi = 0; mi < 4; ++mi) {
        float4 bs = *(const float4*)(bias + h * HD + mi * 16 + quad * 4);
        #pragma unroll
        for (int ni = 0; ni < 4; ++ni)
            *(uint2*)(qs + (ni * 16 + l16) * 72 + mi * 16 + quad * 4) =
                pack4((qacc[mi][ni][0] + bs.x) * QSCALE,
                      (qacc[mi][ni][1] + bs.y) * QSCALE,
                      (qacc[mi][ni][2] + bs.z) * QSCALE,
                      (qacc[mi][ni][3] + bs.w) * QSCALE);
    }
    // read back as 32x32x16 B-frags: B[n=q=l32][k=c' chunk kk*16+hl*8]
    bf16x8 qf[2][4];
    #pragma unroll
    for (int ni = 0; ni < 2; ++ni)
        #pragma unroll
        for (int kk = 0; kk < 4; ++kk)
            qf[ni][kk] = lds8(qs + (ni * 32 + l32) * 72 + kk * 16 + hl * 8);

    // ---- K-GEMM: A=Wk (m=c'), B=xf. Epi overwrites own kc slice.
    {
        f32x4 kacc[4][4];
        #pragma unroll
        for (int mi = 0; mi < 4; ++mi)
            #pragma unroll
            for (int nt = 0; nt < 4; ++nt) kacc[mi][nt] = z4;
        #pragma unroll
        for (int kk = 0; kk < 4; ++kk)
            #pragma unroll
            for (int mi = 0; mi < 4; ++mi) {
                bf16x8 a = ldg8(Wk + (size_t)(mi * 16 + l16) * C + kk * 32 + quad * 8);
                #pragma unroll
                for (int nt = 0; nt < 4; ++nt)
                    kacc[mi][nt] = MFMA16(a, xf[nt][kk], kacc[mi][nt]);
            }
        // C/D col=g=l16, row=c' -> kc[g][c']
        #pragma unroll
        for (int mi = 0; mi < 4; ++mi) {
            float4 bs = *(const float4*)(bias + C + h * HD + mi * 16 + quad * 4);
            #pragma unroll
            for (int nt = 0; nt < 4; ++nt)
                *(uint2*)(kc + (r0 + nt * 16 + l16) * 72 + mi * 16 + quad * 4) =
                    pack4(kacc[mi][nt][0] + bs.x, kacc[mi][nt][1] + bs.y,
                          kacc[mi][nt][2] + bs.z, kacc[mi][nt][3] + bs.w);
        }
    }

    // ---- V-GEMM: A=xf (m=tok), B=Wv (n=c'). Epi: disjoint vc columns.
    {
        f32x4 vacc[4][4];
        #pragma unroll
        for (int mt = 0; mt < 4; ++mt)
            #pragma unroll
            for (int nt = 0; nt < 4; ++nt) vacc[mt][nt] = z4;
        #pragma unroll
        for (int kk = 0; kk < 4; ++kk)
            #pragma unroll
            for (int nt = 0; nt < 4; ++nt) {
                bf16x8 bw = ldg8(Wv + (size_t)(nt * 16 + l16) * C + kk * 32 + quad * 8);
                #pragma unroll
                for (int mt = 0; mt < 4; ++mt)
                    vacc[mt][nt] = MFMA16(xf[mt][kk], bw, vacc[mt][nt]);
            }
        // C/D col=c'=l16, row=g -> vc[c'][g]
        #pragma unroll
        for (int nt = 0; nt < 4; ++nt) {
            float bv = bias[2 * C + h * HD + nt * 16 + l16];
            #pragma unroll
            for (int mt = 0; mt < 4; ++mt)
                *(uint2*)(vc + (nt * 16 + l16) * 264 + r0 + mt * 16 + quad * 4) =
                    pack4(vacc[mt][nt][0] + bv, vacc[mt][nt][1] + bv,
                          vacc[mt][nt][2] + bv, vacc[mt][nt][3] + bv);
        }
    }

    __syncthreads();   // K/V tiles ready for all waves (the only barrier)

    // ---- attention, 32x32x16. Wave's 64 queries = two 32-col tiles (ni).
    // Strip order STAGGERED per wave and per block so co-resident waves sit
    // in different micro-phases (stall de-correlation).
    float lacc[2] = {0.f, 0.f};
    f32x16 oacc[2][2];
    #pragma unroll
    for (int mt = 0; mt < 2; ++mt)
        #pragma unroll
        for (int ni = 0; ni < 2; ++ni)
            #pragma unroll
            for (int r = 0; r < 16; ++r) oacc[mt][ni][r] = 0.f;

    const int spoff = 2 * wv + ((b & 1) << 2);

    #pragma unroll 2
    for (int sp = 0; sp < 8; ++sp) {
        const int g0 = ((sp + spoff) & 7) * 32;

        bf16x8 kf[4];             // A[m=g_k=l32][k=c' chunk kk*16+hl*8]
        #pragma unroll
        for (int kk = 0; kk < 4; ++kk)
            kf[kk] = lds8(kc + (g0 + l32) * 72 + kk * 16 + hl * 8);
        bf16x8 vf[2][2];          // A[m=c'=mt*32+l32][k=g_k chunk ch*16+hl*8]
        #pragma unroll
        for (int mt = 0; mt < 2; ++mt)
            #pragma unroll
            for (int ch = 0; ch < 2; ++ch)
                vf[mt][ch] = lds8(vc + (mt * 32 + l32) * 264 + g0 + ch * 16 + hl * 8);

        #pragma unroll
        for (int ni = 0; ni < 2; ++ni) {
            f32x16 s;
            #pragma unroll
            for (int r = 0; r < 16; ++r) s[r] = 0.f;
            __builtin_amdgcn_s_setprio(1);
            #pragma unroll
            for (int kk = 0; kk < 4; ++kk)
                s = MFMA32(kf[kk], qf[ni][kk], s);
            __builtin_amdgcn_s_setprio(0);

            // softmax: p = exp2(s) lane-local (each lane = one query column)
            float part = 0.f;
            #pragma unroll
            for (int r = 0; r < 16; ++r) {
                float p = __builtin_amdgcn_exp2f(s[r]);
                s[r] = p;
                part += p;
            }
            lacc[ni] += part;

            // P -> PV B-frag IN REGISTERS: cvt_pk pairs + permlane32_swap.
            #pragma unroll
            for (int ch = 0; ch < 2; ++ch) {
                unsigned p0a = pack2(s[8 * ch + 0], s[8 * ch + 1]);
                unsigned p0b = pack2(s[8 * ch + 2], s[8 * ch + 3]);
                unsigned p1a = pack2(s[8 * ch + 4], s[8 * ch + 5]);
                unsigned p1b = pack2(s[8 * ch + 6], s[8 * ch + 7]);
                auto w02 = __builtin_amdgcn_permlane32_swap((int)p0a, (int)p1a, false, false);
                auto w13 = __builtin_amdgcn_permlane32_swap((int)p0b, (int)p1b, false, false);
                union { uint4 u; bf16x8 v; } pf;
                pf.u.x = (unsigned)w02[0]; pf.u.y = (unsigned)w13[0];
                pf.u.z = (unsigned)w02[1]; pf.u.w = (unsigned)w13[1];
                __builtin_amdgcn_s_setprio(1);
                #pragma unroll
                for (int mt = 0; mt < 2; ++mt)
                    oacc[mt][ni] = MFMA32(vf[mt][ch], pf.v, oacc[mt][ni]);
                __builtin_amdgcn_s_setprio(0);
            }
        }
    }

    // epilogue: out[bl, g, h*64+c']; O^T C/D: col=q=l32, row=c'=4rr..+4hl+32mt
    float* og = out + (size_t)bl * G * C + h * HD;
    #pragma unroll
    for (int ni = 0; ni < 2; ++ni) {
        float l = lacc[ni];
        l += __shfl_xor(l, 32);          // rows split only across lane halves
        float inv = 1.0f / l;
        int g = r0 + ni * 32 + l32;
        #pragma unroll
        for (int mt = 0; mt < 2; ++mt)
            #pragma unroll
            for (int rr = 0; rr < 4; ++rr) {
                float4 st;
                st.x = oacc[mt][ni][4 * rr + 0] * inv;
                st.y = oacc[mt][ni][4 * rr + 1] * inv;
                st.z = oacc[mt][ni][4 * rr + 2] * inv;
                st.w = oacc[mt][ni][4 * rr + 3] * inv;
                *(float4*)(og + (size_t)g * C + mt * 32 + rr * 8 + hl * 4) = st;
            }
    }
}

} // namespace dmsa

extern "C" void kernel_launch(void* const* d_in, const int* in_sizes, int n_in,
                              void* d_out, int out_size, void* d_ws, size_t ws_size,
                              hipStream_t stream) {
    (void)in_sizes; (void)n_in; (void)out_size;

    if (ws_size < (size_t)384 * 128 * 2) return;   // 96 KB W-bf16 scratch

    const float* x    = (const float*)d_in[0];
    const float* W    = (const float*)d_in[1];
    const float* bias = (const float*)d_in[2];
    float* out = (float*)d_out;

    ushort* wbf = (ushort*)d_ws;

    dmsa::convw<<<dim3(24),   dim3(256), 0, stream>>>(W, wbf);
    dmsa::fused<<<dim3(1024), dim3(256), 0, stream>>>(x, wbf, bias, out);
}